// Round 7
// baseline (775.384 us; speedup 1.0000x reference)
//
#include <hip/hip_runtime.h>
#include <cstdint>

#define DEV static __device__ __forceinline__

typedef __attribute__((ext_vector_type(8))) short bf16x8;
typedef __attribute__((ext_vector_type(4))) short bf16x4;
typedef __attribute__((ext_vector_type(4))) float f32x4;

// ---------------- problem constants ----------------
constexpr int BATCH = 2;
constexpr int G0 = 80;
constexpr int D1 = 78, D2 = 76, D3 = 74;
constexpr int C = 32;
constexpr int SD = 64, NSLOT = 8;
constexpr int D1S = D1 * D1 * D1;      // 474552
constexpr int D2S = D2 * D2 * D2;      // 438976
constexpr int D3S = D3 * D3 * D3;      // 405224
constexpr int NPOS1 = BATCH * D1S;
constexpr int NCHUNK = (D3S + 255) / 256;   // 1583
constexpr int ATTN_TOTBLK = NCHUNK * BATCH;
constexpr int NRED = 32;
constexpr int REDS = 544;                   // 512 upd + 16 rowsum + pad

// ---------------- workspace layout (bytes) ----------------
constexpr size_t A1_BYTES = (size_t)NPOS1 * C * 2;           // 60.7 MB
constexpr size_t A2_BYTES = (size_t)BATCH * D2S * C * 2;     // 56.2 MB
constexpr size_t S_OFF    = A1_BYTES + A2_BYTES;             // ~117 MB

DEV unsigned short f2bf(float f) {
  unsigned int u = __float_as_uint(f);
  u += 0x7fffu + ((u >> 16) & 1u);
  return (unsigned short)(u >> 16);
}
DEV unsigned int pk2(float a, float b) {
  return (unsigned int)f2bf(a) | ((unsigned int)f2bf(b) << 16);
}
DEV float bflo(unsigned int u) { return __uint_as_float(u << 16); }
DEV float bfhi(unsigned int u) { return __uint_as_float(u & 0xffff0000u); }
DEV float bfu(unsigned short h) { return __uint_as_float(((unsigned int)h) << 16); }

// ---------------- weight prep ----------------
__global__ __launch_bounds__(256) void k_wtr(const float* __restrict__ w1,
                                             const float* __restrict__ w2,
                                             const float* __restrict__ w3,
                                             unsigned short* __restrict__ wB1,
                                             unsigned short* __restrict__ wB2,
                                             unsigned short* __restrict__ wB3) {
  int idx = blockIdx.x * 256 + threadIdx.x;
  if (idx < 4096) {
    int co = idx >> 7, k = idx & 127;
    int tap = k >> 2, ci = k & 3;
    wB1[idx] = (tap < 27) ? f2bf(w1[co * 108 + ci * 27 + tap]) : (unsigned short)0;
  }
  int i2 = idx - 4096;
  if (i2 >= 0 && i2 < 27648) {
    int ci = i2 & 31, co = (i2 >> 5) & 31, tap = i2 >> 10;
    wB2[i2] = f2bf(w2[(co * 32 + ci) * 27 + tap]);
  }
  int i3 = idx - 4096 - 27648;
  if (i3 >= 0 && i3 < 27648) {
    int ci = i3 & 31, co = (i3 >> 5) & 31, tap = i3 >> 10;
    wB3[i3] = f2bf(w3[(co * 32 + ci) * 27 + tap]);
  }
}

// ---------------- conv1 via MFMA ----------------
constexpr int C1NX = 5, C1NY = 20, C1NZ = 20;
__global__ __launch_bounds__(256) void k_conv1m(const float* __restrict__ in,
                                                const unsigned short* __restrict__ wB1,
                                                const float* __restrict__ bias,
                                                unsigned short* __restrict__ out) {
  __shared__ char smemc[256 * 34 * 4];
  unsigned short* raw = (unsigned short*)smemc;
  int bid = blockIdx.x;
  int b = bid / (C1NX * C1NY * C1NZ);
  int t = bid % (C1NX * C1NY * C1NZ);
  int tx = t % C1NX;
  int ty = (t / C1NX) % C1NY;
  int tz = t / (C1NX * C1NY);
  int x0 = tx * 16, y0 = ty * 4, z0 = tz * 4;
  int tid = threadIdx.x;

  const float* ib = in + (size_t)b * 4 * (G0 * G0 * G0);
  for (int p = tid; p < 648; p += 256) {
    int xl = p % 18, yl = (p / 18) % 6, zl = p / 108;
    int xg = min(x0 + xl, G0 - 1);
    int yg = min(y0 + yl, G0 - 1);
    int zg = min(z0 + zl, G0 - 1);
    size_t base = ((size_t)zg * G0 + yg) * G0 + xg;
    float v0 = ib[base];
    float v1 = ib[base + 512000];
    float v2 = ib[base + 2 * 512000];
    float v3 = ib[base + 3 * 512000];
    uint2 pk = {pk2(v0, v1), pk2(v2, v3)};
    *(uint2*)(raw + p * 4) = pk;
  }
  __syncthreads();

  int wv = tid >> 6, ln = tid & 63, q = ln >> 4, mr = ln & 15;

  bf16x8 Bf[4][2];
#pragma unroll
  for (int s = 0; s < 4; s++)
#pragma unroll
    for (int nt = 0; nt < 2; nt++)
      Bf[s][nt] = *(const bf16x8*)(wB1 + (nt * 16 + mr) * 128 + s * 32 + q * 8);

  f32x4 acc[4][2];
#pragma unroll
  for (int mi = 0; mi < 4; mi++)
#pragma unroll
    for (int nt = 0; nt < 2; nt++) acc[mi][nt] = (f32x4){0.f, 0.f, 0.f, 0.f};

#pragma unroll
  for (int s = 0; s < 4; s++) {
    int tA = min(s * 8 + q * 2, 26);
    int tB = min(s * 8 + q * 2 + 1, 26);
    int oA = (tA / 9) * 108 + ((tA / 3) % 3) * 18 + (tA % 3);
    int oB = (tB / 9) * 108 + ((tB / 3) % 3) * 18 + (tB % 3);
#pragma unroll
    for (int mi = 0; mi < 4; mi++) {
      int pbase = wv * 108 + mi * 18 + mr;
      bf16x8 af;
      *(bf16x4*)&af = *(const bf16x4*)(raw + (pbase + oA) * 4);
      *((bf16x4*)&af + 1) = *(const bf16x4*)(raw + (pbase + oB) * 4);
      acc[mi][0] = __builtin_amdgcn_mfma_f32_16x16x32_bf16(af, Bf[s][0], acc[mi][0], 0, 0, 0);
      acc[mi][1] = __builtin_amdgcn_mfma_f32_16x16x32_bf16(af, Bf[s][1], acc[mi][1], 0, 0, 0);
    }
  }

  __syncthreads();
  float* sout = (float*)smemc;
#pragma unroll
  for (int mi = 0; mi < 4; mi++) {
    int mtile = wv * 4 + mi;
#pragma unroll
    for (int nt = 0; nt < 2; nt++) {
#pragma unroll
      for (int r = 0; r < 4; r++) {
        int pl = mtile * 16 + q * 4 + r;
        sout[pl * 34 + nt * 16 + mr] = acc[mi][nt][r];
      }
    }
  }
  __syncthreads();

  int xl = tid & 15, yl = (tid >> 4) & 3, zl = tid >> 6;
  int xg = x0 + xl, yg = y0 + yl, zg = z0 + zl;
  if (xg < D1 && yg < D1 && zg < D1) {
    float v[C];
#pragma unroll
    for (int c = 0; c < C; c++) v[c] = fmaxf(sout[tid * 34 + c] + bias[c], 0.f);
    unsigned short* op = out + ((size_t)b * D1S + (size_t)zg * (D1 * D1) + (size_t)yg * D1 + xg) * C;
#pragma unroll
    for (int g = 0; g < 4; g++) {
      uint4 o;
      o.x = pk2(v[g * 8 + 0], v[g * 8 + 1]);
      o.y = pk2(v[g * 8 + 2], v[g * 8 + 3]);
      o.z = pk2(v[g * 8 + 4], v[g * 8 + 5]);
      o.w = pk2(v[g * 8 + 6], v[g * 8 + 7]);
      ((uint4*)op)[g] = o;
    }
  }
}

// ---------------- MFMA implicit-GEMM conv (32->32) ----------------
template <int DIN, int DOUT, bool DO_LN>
__global__ __launch_bounds__(256) void k_convm(const unsigned short* __restrict__ actin,
                                               const unsigned short* __restrict__ wB,
                                               const float* __restrict__ bias,
                                               const float* __restrict__ lng,
                                               const float* __restrict__ lnb,
                                               unsigned short* __restrict__ actout) {
  constexpr int DIN2 = DIN * DIN;
  constexpr size_t DINS = (size_t)DIN * DIN2;
  constexpr int DOUT2 = DOUT * DOUT;
  constexpr size_t DOUTS = (size_t)DOUT * DOUT2;
  constexpr int NX = (DOUT + 15) / 16, NY = (DOUT + 3) / 4, NZ = (DOUT + 3) / 4;

  __shared__ alignas(16) unsigned short s_halo[648 * 32];

  int bid = blockIdx.x;
  int b = bid / (NX * NY * NZ);
  int t = bid % (NX * NY * NZ);
  int tx = t % NX;
  int t2 = t / NX;
  int ty = t2 % NY;
  int tz = t2 / NY;
  int x0 = tx * 16, y0 = ty * 4, z0 = tz * 4;
  const unsigned short* ib = actin + (size_t)b * DINS * 32;

  int tid = threadIdx.x;
  for (int ck = tid; ck < 2592; ck += 256) {
    int pos = ck >> 2, sub = ck & 3;
    int xl = pos % 18;
    int p2 = pos / 18;
    int yl = p2 % 6;
    int zl = p2 / 6;
    int xg = min(x0 + xl, DIN - 1);
    int yg = min(y0 + yl, DIN - 1);
    int zg = min(z0 + zl, DIN - 1);
    uint4 v = *(const uint4*)(ib + ((size_t)zg * DIN2 + (size_t)yg * DIN + xg) * 32 + sub * 8);
    *(uint4*)(s_halo + pos * 32 + sub * 8) = v;
  }
  __syncthreads();

  int wv = tid >> 6, ln = tid & 63, q = ln >> 4, mr = ln & 15;

  f32x4 acc[4][2];
#pragma unroll
  for (int mi = 0; mi < 4; mi++)
#pragma unroll
    for (int nt = 0; nt < 2; nt++) acc[mi][nt] = (f32x4){0.f, 0.f, 0.f, 0.f};

  bf16x8 B0 = *(const bf16x8*)(wB + mr * 32 + q * 8);
  bf16x8 B1 = *(const bf16x8*)(wB + (16 + mr) * 32 + q * 8);
#pragma unroll
  for (int tap = 0; tap < 27; tap++) {
    int dz = tap / 9, dy = (tap / 3) % 3, dx = tap % 3;
    bf16x8 nB0, nB1;
    if (tap < 26) {
      nB0 = *(const bf16x8*)(wB + (tap + 1) * 1024 + mr * 32 + q * 8);
      nB1 = *(const bf16x8*)(wB + (tap + 1) * 1024 + (16 + mr) * 32 + q * 8);
    }
#pragma unroll
    for (int mi = 0; mi < 4; mi++) {
      bf16x8 Af = *(const bf16x8*)(s_halo +
          ((wv + dz) * 108 + (mi + dy) * 18 + (mr + dx)) * 32 + q * 8);
      acc[mi][0] = __builtin_amdgcn_mfma_f32_16x16x32_bf16(Af, B0, acc[mi][0], 0, 0, 0);
      acc[mi][1] = __builtin_amdgcn_mfma_f32_16x16x32_bf16(Af, B1, acc[mi][1], 0, 0, 0);
    }
    if (tap < 26) { B0 = nB0; B1 = nB1; }
  }

  __syncthreads();
  float* s_out = (float*)s_halo;
#pragma unroll
  for (int mi = 0; mi < 4; mi++) {
    int mtile = wv * 4 + mi;
#pragma unroll
    for (int nt = 0; nt < 2; nt++) {
#pragma unroll
      for (int r = 0; r < 4; r++) {
        int pl = mtile * 16 + q * 4 + r;
        s_out[pl * 34 + nt * 16 + mr] = acc[mi][nt][r];
      }
    }
  }
  __syncthreads();

  int xl = tid & 15, yl = (tid >> 4) & 3, zl = tid >> 6;
  int xg = x0 + xl, yg = y0 + yl, zg = z0 + zl;
  bool valid = (xg < DOUT) && (yg < DOUT) && (zg < DOUT);
  float v[C];
  float s = 0.f, s2 = 0.f;
#pragma unroll
  for (int c = 0; c < C; c++) {
    float x = fmaxf(s_out[tid * 34 + c] + bias[c], 0.f);
    v[c] = x;
    s += x; s2 += x * x;
  }
  if (DO_LN) {
    float m = s * (1.f / C);
    float inv = rsqrtf(s2 * (1.f / C) - m * m + 1e-5f);
#pragma unroll
    for (int c = 0; c < C; c++) v[c] = (v[c] - m) * inv * lng[c] + lnb[c];
  }
  if (valid) {
    unsigned short* op = actout + ((size_t)b * DOUTS + (size_t)zg * DOUT2 + (size_t)yg * DOUT + xg) * 32;
#pragma unroll
    for (int g = 0; g < 4; g++) {
      uint4 o;
      o.x = pk2(v[g * 8 + 0], v[g * 8 + 1]);
      o.y = pk2(v[g * 8 + 2], v[g * 8 + 3]);
      o.z = pk2(v[g * 8 + 4], v[g * 8 + 5]);
      o.w = pk2(v[g * 8 + 6], v[g * 8 + 7]);
      ((uint4*)op)[g] = o;
    }
  }
}

// ---------------- initial qprep: qkB bf16 [b][16][32] + zero red/ctr ----------------
__global__ __launch_bounds__(256) void k_qprep(const float* __restrict__ slots_src,
                                               const float* __restrict__ qlng,
                                               const float* __restrict__ qlnb,
                                               const float* __restrict__ qw,
                                               const float* __restrict__ kw,
                                               unsigned short* __restrict__ qkB,
                                               float* __restrict__ red,
                                               unsigned int* __restrict__ ctr) {
  __shared__ float ln_s[16][SD];
  __shared__ float q_s[16][SD];
  __shared__ float mv[16][2];
  int tid = threadIdx.x;
  for (int o = tid; o < NRED * REDS; o += 256) red[o] = 0.f;
  if (tid == 0) ctr[0] = 0u;
  if (tid < 16) {
    float s = 0.f, s2 = 0.f;
    for (int c = 0; c < SD; c++) { float v = slots_src[tid * SD + c]; s += v; s2 += v * v; }
    float m = s * (1.f / SD);
    mv[tid][0] = m;
    mv[tid][1] = rsqrtf(s2 * (1.f / SD) - m * m + 1e-5f);
  }
  __syncthreads();
  for (int idx = tid; idx < 16 * SD; idx += 256) {
    int r = idx >> 6, c = idx & 63;
    ln_s[r][c] = (slots_src[idx] - mv[r][0]) * mv[r][1] * qlng[c] + qlnb[c];
  }
  __syncthreads();
  for (int o = tid; o < 16 * SD; o += 256) {
    int r = o >> 6, d = o & 63;
    float s = 0.f;
    for (int c = 0; c < SD; c++) s = fmaf(ln_s[r][c], qw[d * SD + c], s);
    q_s[r][d] = s;
  }
  __syncthreads();
  for (int o = tid; o < 1024; o += 256) {
    int b = o >> 9, i = (o >> 5) & 15, c = o & 31;
    unsigned short v = 0;
    if (i < 8) {
      float s = 0.f;
      for (int d = 0; d < SD; d++) s = fmaf(q_s[(b * 8 + i)][d], kw[d * C + c], s);
      v = f2bf(s);
    }
    qkB[o] = v;
  }
}

// ---------------- fused attention (MFMA dots, vectorized phase2) + ticket final ----------------
__global__ __launch_bounds__(256) void k_attn(const unsigned short* __restrict__ feat,
                                              unsigned short* __restrict__ qkB,
                                              float* __restrict__ red,
                                              unsigned int* __restrict__ ctr,
                                              float* __restrict__ attn_out,
                                              const float* __restrict__ slots_src,
                                              float* __restrict__ slots_dst,
                                              float* __restrict__ out_slots,
                                              const float* __restrict__ vw,
                                              const float* __restrict__ wih,
                                              const float* __restrict__ whh,
                                              const float* __restrict__ bih,
                                              const float* __restrict__ bhh,
                                              const float* __restrict__ rlng,
                                              const float* __restrict__ rlnb,
                                              const float* __restrict__ w1,
                                              const float* __restrict__ rb1,
                                              const float* __restrict__ w2,
                                              const float* __restrict__ rb2,
                                              const float* __restrict__ qlng,
                                              const float* __restrict__ qlnb,
                                              const float* __restrict__ qw,
                                              const float* __restrict__ kw,
                                              int last) {
  // f_s: 256 rows x 80B (bf16, 16B-chunks, 2-way banks) = 20480
  // dots_s: 256 rows x 48B (fp32, 8 used)              = 12288 @ 20480
  // a_s: 8 x 264 bf16 (pad every 32)                   = 4224  @ 32768
  __shared__ alignas(16) char smem[36992];
  __shared__ int lastFlag;
  char* f_s = smem;
  float* dots_s = (float*)(smem + 20480);
  unsigned short* a_s = (unsigned short*)(smem + 32768);

  int tid = threadIdx.x;
  int b = blockIdx.y;
  int wv = tid >> 6, ln = tid & 63, q = ln >> 4, mr = ln & 15;

  int j0 = blockIdx.x * 256;
  int j = j0 + tid;
  bool valid = j < D3S;

  // phase 0: global feat -> LDS rows (packed bf16)
  uint4 f4[4];
  if (valid) {
    const uint4* fp = (const uint4*)(feat + ((size_t)b * D3S + j) * C);
#pragma unroll
    for (int g = 0; g < 4; g++) f4[g] = fp[g];
  } else {
#pragma unroll
    for (int g = 0; g < 4; g++) f4[g] = (uint4){0u, 0u, 0u, 0u};
  }
#pragma unroll
  for (int g = 0; g < 4; g++) *(uint4*)(f_s + tid * 80 + g * 16) = f4[g];

  // B-frag: qkB[b][n=slot(16)][k=c(32)] bf16
  bf16x8 Bq = *(const bf16x8*)(qkB + b * 512 + mr * 32 + q * 8);
  __syncthreads();

  // phase 1: dots via MFMA (4 m-tiles per wave cover this wave's 64 j)
  f32x4 dacc[4];
#pragma unroll
  for (int mt = 0; mt < 4; mt++) {
    bf16x8 Af = *(const bf16x8*)(f_s + (wv * 64 + mt * 16 + mr) * 80 + q * 16);
    dacc[mt] = __builtin_amdgcn_mfma_f32_16x16x32_bf16(
        Af, Bq, (f32x4){0.f, 0.f, 0.f, 0.f}, 0, 0, 0);
  }
  if (mr < 8) {
#pragma unroll
    for (int mt = 0; mt < 4; mt++)
#pragma unroll
      for (int r = 0; r < 4; r++)
        dots_s[(wv * 64 + mt * 16 + q * 4 + r) * 12 + mr] = dacc[mt][r];
  }
  __syncthreads();

  // softmax over slots (thread = its j)
  float attn[NSLOT];
  {
    uint4 d0 = *(const uint4*)(dots_s + tid * 12);
    uint4 d1 = *(const uint4*)(dots_s + tid * 12 + 4);
    float dot[NSLOT] = {__uint_as_float(d0.x), __uint_as_float(d0.y),
                        __uint_as_float(d0.z), __uint_as_float(d0.w),
                        __uint_as_float(d1.x), __uint_as_float(d1.y),
                        __uint_as_float(d1.z), __uint_as_float(d1.w)};
    float mx = -1e30f;
#pragma unroll
    for (int i = 0; i < NSLOT; i++) { dot[i] *= 0.125f; mx = fmaxf(mx, dot[i]); }
    float ssum = 0.f;
#pragma unroll
    for (int i = 0; i < NSLOT; i++) { float e = __expf(dot[i] - mx); attn[i] = e; ssum += e; }
    float invs = 1.f / ssum;
#pragma unroll
    for (int i = 0; i < NSLOT; i++)
      attn[i] = valid ? fmaf(attn[i], invs, 1e-8f) : 0.f;
  }
#pragma unroll
  for (int i = 0; i < NSLOT; i++)
    a_s[i * 264 + tid + (tid >> 5)] = f2bf(attn[i]);
  if (last && valid) {
#pragma unroll
    for (int i = 0; i < NSLOT; i++)
      attn_out[(size_t)(b * NSLOT + i) * D3S + j] = attn[i];
  }
  __syncthreads();

  // phase 2: thread = (i0 slot, cg 8-ch group, jq stripe); j = it*8+jq
  int i0 = tid >> 5;
  int cg = (tid >> 3) & 3;
  int jq = tid & 7;
  float acc[8];
#pragma unroll
  for (int t = 0; t < 8; t++) acc[t] = 0.f;
  float rs = 0.f;
#pragma unroll 4
  for (int it = 0; it < 32; it++) {
    int jj = it * 8 + jq;
    float a = bfu(a_s[i0 * 264 + jj + (jj >> 5)]);
    uint4 fv = *(const uint4*)(f_s + jj * 80 + cg * 16);
    acc[0] = fmaf(a, bflo(fv.x), acc[0]);
    acc[1] = fmaf(a, bfhi(fv.x), acc[1]);
    acc[2] = fmaf(a, bflo(fv.y), acc[2]);
    acc[3] = fmaf(a, bfhi(fv.y), acc[3]);
    acc[4] = fmaf(a, bflo(fv.z), acc[4]);
    acc[5] = fmaf(a, bfhi(fv.z), acc[5]);
    acc[6] = fmaf(a, bflo(fv.w), acc[6]);
    acc[7] = fmaf(a, bfhi(fv.w), acc[7]);
    rs += a;
  }
#pragma unroll
  for (int d = 1; d < 8; d <<= 1) {
#pragma unroll
    for (int t = 0; t < 8; t++) acc[t] += __shfl_xor(acc[t], d);
    rs += __shfl_xor(rs, d);
  }
  int gsl = blockIdx.x & (NRED - 1);
  int r = b * NSLOT + i0;
  if (jq == 0) {
#pragma unroll
    for (int t = 0; t < 8; t++)
      atomicAdd(&red[gsl * REDS + r * 32 + cg * 8 + t], acc[t]);
    if (cg == 0) atomicAdd(&red[gsl * REDS + 512 + r], rs);
  }

  // ---- ticket (atomics coherent at LLC; just drain vmcnt) ----
  asm volatile("s_waitcnt vmcnt(0)" ::: "memory");
  if (tid == 0) {
    unsigned tkt = atomicAdd(ctr, 1u);
    lastFlag = (tkt == (unsigned)(ATTN_TOTBLK - 1));
  }
  __syncthreads();
  if (!lastFlag) return;

  // ---- final phase (single block), aliased (fits 35KB) ----
  float* sm    = (float*)smem;
  float* updc  = sm;            // 528   live -> upd_s pass
  float* rs_s  = sm + 528;      // 16    live -> upd_s pass
  float* hh    = sm + 544;      // 1024  live -> gate pass
  float* upd_s = sm + 1568;     // 1024  live -> xg/hg pass
  float* xg    = sm + 2592;     // 3072  live -> gate pass
  float* hg    = sm + 5664;     // 3072  live -> gate pass
  float* hn    = sm;            // 1024  (over updc/rs_s, dead) written in gate pass
  float* mv    = sm + 1024;     // 32
  float* tl    = sm + 1568;     // 1024  (over upd_s, dead)
  float* m1    = sm + 2592;     // 2048  (over xg, dead)
  float* stash = sm + 4640;     // 1024  (over xg tail, dead)
  float* qbuf  = sm + 5664;     // 1024  (over hg, dead)

  if (tid < 16) {
    float sr = 0.f;
#pragma unroll
    for (int g = 0; g < NRED; g++) sr += atomicAdd(&red[g * REDS + 512 + tid], 0.f);
    rs_s[tid] = sr;
  }
  for (int o = tid; o < 512; o += 256) {
    float s = 0.f;
#pragma unroll
    for (int g = 0; g < NRED; g++) s += atomicAdd(&red[g * REDS + o], 0.f);
    updc[(o >> 5) * 33 + (o & 31)] = s;
  }
  for (int idx = tid; idx < 1024; idx += 256) hh[idx] = slots_src[idx];
  __syncthreads();
  for (int o = tid; o < 1024; o += 256) {
    int rr = o >> 6, dd = o & 63;
    float s = 0.f;
    for (int cc = 0; cc < 32; cc++) s = fmaf(updc[rr * 33 + cc], vw[dd * 32 + cc], s);
    upd_s[o] = s / rs_s[rr];
  }
  __syncthreads();
  for (int o = tid; o < 6144; o += 256) {
    int sel = o >= 3072;
    int oo = o - sel * 3072;
    int rr = oo / 192, cg2 = oo % 192;
    const float* sp = sel ? &hh[rr * 64] : &upd_s[rr * 64];
    const float* w = sel ? whh : wih;
    float s = sel ? bhh[cg2] : bih[cg2];
    for (int dd = 0; dd < 64; dd++) s = fmaf(sp[dd], w[cg2 * 64 + dd], s);
    float* dp = sel ? hg : xg;
    dp[rr * 192 + cg2] = s;
  }
  __syncthreads();
  for (int idx = tid; idx < 1024; idx += 256) {
    int rr = idx >> 6, dd = idx & 63;
    float rg = 1.f / (1.f + __expf(-(xg[rr * 192 + dd] + hg[rr * 192 + dd])));
    float zg_ = 1.f / (1.f + __expf(-(xg[rr * 192 + 64 + dd] + hg[rr * 192 + 64 + dd])));
    float ng = tanhf(xg[rr * 192 + 128 + dd] + rg * hg[rr * 192 + 128 + dd]);
    hn[idx] = (1.f - zg_) * ng + zg_ * hh[idx];
  }
  __syncthreads();
  if (tid < 16) {
    float s = 0.f, s2 = 0.f;
    for (int cc = 0; cc < 64; cc++) { float v = hn[tid * 64 + cc]; s += v; s2 += v * v; }
    float m = s * (1.f / 64);
    mv[tid * 2] = m;
    mv[tid * 2 + 1] = rsqrtf(s2 * (1.f / 64) - m * m + 1e-5f);
  }
  __syncthreads();
  for (int idx = tid; idx < 1024; idx += 256) {
    int rr = idx >> 6, dd = idx & 63;
    tl[idx] = (hn[idx] - mv[rr * 2]) * mv[rr * 2 + 1] * rlng[dd] + rlnb[dd];
  }
  __syncthreads();
  for (int o = tid; o < 2048; o += 256) {
    int rr = o >> 7, jj = o & 127;
    float s = rb1[jj];
    for (int dd = 0; dd < 64; dd++) s = fmaf(tl[rr * 64 + dd], w1[jj * 64 + dd], s);
    m1[o] = fmaxf(s, 0.f);
  }
  __syncthreads();
  for (int idx = tid; idx < 1024; idx += 256) {
    int rr = idx >> 6, dd = idx & 63;
    float s = rb2[dd];
    for (int jj = 0; jj < 128; jj++) s = fmaf(m1[rr * 128 + jj], w2[dd * 128 + jj], s);
    float outv = hn[idx] + s;
    slots_dst[idx] = outv;
    stash[idx] = outv;
    if (last) out_slots[idx] = outv;
  }
  __syncthreads();
  // next-iter qprep
  if (tid < 16) {
    float s = 0.f, s2 = 0.f;
    for (int cc = 0; cc < 64; cc++) { float v = stash[tid * 64 + cc]; s += v; s2 += v * v; }
    float m = s * (1.f / 64);
    mv[tid * 2] = m;
    mv[tid * 2 + 1] = rsqrtf(s2 * (1.f / 64) - m * m + 1e-5f);
  }
  __syncthreads();
  for (int idx = tid; idx < 1024; idx += 256) {
    int rr = idx >> 6, dd = idx & 63;
    tl[idx] = (stash[idx] - mv[rr * 2]) * mv[rr * 2 + 1] * qlng[dd] + qlnb[dd];
  }
  __syncthreads();
  for (int o = tid; o < 1024; o += 256) {
    int rr = o >> 6, d = o & 63;
    float s = 0.f;
    for (int cc = 0; cc < 64; cc++) s = fmaf(tl[rr * 64 + cc], qw[d * 64 + cc], s);
    qbuf[o] = s;
  }
  __syncthreads();
  for (int o = tid; o < 1024; o += 256) {
    int bb = o >> 9, ii = (o >> 5) & 15, cc = o & 31;
    unsigned short v = 0;
    if (ii < 8) {
      float s = 0.f;
      for (int d = 0; d < 64; d++) s = fmaf(qbuf[(bb * 8 + ii) * 64 + d], kw[d * 32 + cc], s);
      v = f2bf(s);
    }
    qkB[o] = v;
  }
  for (int o = tid; o < NRED * REDS; o += 256) red[o] = 0.f;
  if (tid == 0) ctr[0] = 0u;
}

// ---------------- host launch ----------------
extern "C" void kernel_launch(void* const* d_in, const int* in_sizes, int n_in,
                              void* d_out, int out_size, void* d_ws, size_t ws_size,
                              hipStream_t stream) {
  const float* slots = (const float*)d_in[0];
  const float* oin   = (const float*)d_in[1];
  const float* w1    = (const float*)d_in[2];
  const float* b1    = (const float*)d_in[3];
  const float* w2    = (const float*)d_in[4];
  const float* b2    = (const float*)d_in[5];
  const float* w3    = (const float*)d_in[6];
  const float* b3    = (const float*)d_in[7];
  const float* kw    = (const float*)d_in[8];
  const float* vw    = (const float*)d_in[9];
  const float* qlng  = (const float*)d_in[10];
  const float* qlnb  = (const float*)d_in[11];
  const float* qw    = (const float*)d_in[12];
  const float* wih   = (const float*)d_in[13];
  const float* whh   = (const float*)d_in[14];
  const float* bih   = (const float*)d_in[15];
  const float* bhh   = (const float*)d_in[16];
  const float* rlng  = (const float*)d_in[17];
  const float* rlnb  = (const float*)d_in[18];
  const float* rw1   = (const float*)d_in[19];
  const float* rb1   = (const float*)d_in[20];
  const float* rw2   = (const float*)d_in[21];
  const float* rb2   = (const float*)d_in[22];
  const float* flng  = (const float*)d_in[23];
  const float* flnb  = (const float*)d_in[24];

  char* ws = (char*)d_ws;
  unsigned short* act1 = (unsigned short*)ws;
  unsigned short* act2 = (unsigned short*)(ws + A1_BYTES);
  unsigned short* feat = act1;
  unsigned short* wB1 = (unsigned short*)(ws + S_OFF);
  unsigned short* wB2 = wB1 + 4096;
  unsigned short* wB3 = wB2 + 27648;
  unsigned short* qkB = wB3 + 27648;           // [2][16][32] bf16 = 1024
  float* red  = (float*)(qkB + 1024);          // NRED*REDS floats
  unsigned int* ctr = (unsigned int*)(red + NRED * REDS);
  float* sl0  = (float*)(ctr + 16);
  float* sl1  = sl0 + 1024;

  float* out_slots = (float*)d_out;
  float* attn_out  = (float*)d_out + 1024;

  k_wtr<<<232, 256, 0, stream>>>(w1, w2, w3, wB1, wB2, wB3);
  k_conv1m<<<C1NX * C1NY * C1NZ * BATCH, 256, 0, stream>>>(oin, wB1, b1, act1);
  {
    constexpr int NB2 = ((D2 + 15) / 16) * ((D2 + 3) / 4) * ((D2 + 3) / 4) * BATCH;
    k_convm<D1, D2, false><<<NB2, 256, 0, stream>>>(act1, wB2, b2, nullptr, nullptr, act2);
  }
  {
    constexpr int NB3 = ((D3 + 15) / 16) * ((D3 + 3) / 4) * ((D3 + 3) / 4) * BATCH;
    k_convm<D2, D3, true><<<NB3, 256, 0, stream>>>(act2, wB3, b3, flng, flnb, feat);
  }

  k_qprep<<<1, 256, 0, stream>>>(slots, qlng, qlnb, qw, kw, qkB, red, ctr);
  const float* src = slots;
  float* dst = sl0;
  for (int it = 0; it < 3; it++) {
    int last = (it == 2);
    k_attn<<<dim3(NCHUNK, BATCH), 256, 0, stream>>>(
        feat, qkB, red, ctr, attn_out,
        src, dst, out_slots,
        vw, wih, whh, bih, bhh, rlng, rlnb, rw1, rb1, rw2, rb2,
        qlng, qlnb, qw, kw, last);
    src = dst;
    dst = (it == 0) ? sl1 : sl0;
  }
}

// Round 8
// 655.975 us; speedup vs baseline: 1.1820x; 1.1820x over previous
//
#include <hip/hip_runtime.h>
#include <cstdint>

#define DEV static __device__ __forceinline__

typedef __attribute__((ext_vector_type(8))) short bf16x8;
typedef __attribute__((ext_vector_type(4))) short bf16x4;
typedef __attribute__((ext_vector_type(4))) float f32x4;

// ---------------- problem constants ----------------
constexpr int BATCH = 2;
constexpr int G0 = 80;
constexpr int D1 = 78, D2 = 76, D3 = 74;
constexpr int C = 32;
constexpr int SD = 64, NSLOT = 8;
constexpr int D1S = D1 * D1 * D1;      // 474552
constexpr int D2S = D2 * D2 * D2;      // 438976
constexpr int D3S = D3 * D3 * D3;      // 405224
constexpr int NPOS1 = BATCH * D1S;
constexpr int NCHUNK = (D3S + 255) / 256;   // 1583
constexpr int NRED = 32;
constexpr int REDS = 544;                   // 512 upd + 16 rowsum + pad

// ---------------- workspace layout (bytes) ----------------
constexpr size_t A1_BYTES = (size_t)NPOS1 * C * 2;           // 60.7 MB
constexpr size_t A2_BYTES = (size_t)BATCH * D2S * C * 2;     // 56.2 MB
constexpr size_t S_OFF    = A1_BYTES + A2_BYTES;             // ~117 MB

DEV unsigned short f2bf(float f) {
  unsigned int u = __float_as_uint(f);
  u += 0x7fffu + ((u >> 16) & 1u);
  return (unsigned short)(u >> 16);
}
DEV unsigned int pk2(float a, float b) {
  return (unsigned int)f2bf(a) | ((unsigned int)f2bf(b) << 16);
}
DEV float bflo(unsigned int u) { return __uint_as_float(u << 16); }
DEV float bfhi(unsigned int u) { return __uint_as_float(u & 0xffff0000u); }
DEV float bfu(unsigned short h) { return __uint_as_float(((unsigned int)h) << 16); }

// ---------------- weight prep ----------------
__global__ __launch_bounds__(256) void k_wtr(const float* __restrict__ w1,
                                             const float* __restrict__ w2,
                                             const float* __restrict__ w3,
                                             unsigned short* __restrict__ wB1,
                                             unsigned short* __restrict__ wB2,
                                             unsigned short* __restrict__ wB3) {
  int idx = blockIdx.x * 256 + threadIdx.x;
  if (idx < 4096) {
    int co = idx >> 7, k = idx & 127;
    int tap = k >> 2, ci = k & 3;
    wB1[idx] = (tap < 27) ? f2bf(w1[co * 108 + ci * 27 + tap]) : (unsigned short)0;
  }
  int i2 = idx - 4096;
  if (i2 >= 0 && i2 < 27648) {
    int ci = i2 & 31, co = (i2 >> 5) & 31, tap = i2 >> 10;
    wB2[i2] = f2bf(w2[(co * 32 + ci) * 27 + tap]);
  }
  int i3 = idx - 4096 - 27648;
  if (i3 >= 0 && i3 < 27648) {
    int ci = i3 & 31, co = (i3 >> 5) & 31, tap = i3 >> 10;
    wB3[i3] = f2bf(w3[(co * 32 + ci) * 27 + tap]);
  }
}

// ---------------- conv1 via MFMA ----------------
constexpr int C1NX = 5, C1NY = 20, C1NZ = 20;
__global__ __launch_bounds__(256) void k_conv1m(const float* __restrict__ in,
                                                const unsigned short* __restrict__ wB1,
                                                const float* __restrict__ bias,
                                                unsigned short* __restrict__ out) {
  __shared__ char smemc[256 * 34 * 4];
  unsigned short* raw = (unsigned short*)smemc;
  int bid = blockIdx.x;
  int b = bid / (C1NX * C1NY * C1NZ);
  int t = bid % (C1NX * C1NY * C1NZ);
  int tx = t % C1NX;
  int ty = (t / C1NX) % C1NY;
  int tz = t / (C1NX * C1NY);
  int x0 = tx * 16, y0 = ty * 4, z0 = tz * 4;
  int tid = threadIdx.x;

  const float* ib = in + (size_t)b * 4 * (G0 * G0 * G0);
  for (int p = tid; p < 648; p += 256) {
    int xl = p % 18, yl = (p / 18) % 6, zl = p / 108;
    int xg = min(x0 + xl, G0 - 1);
    int yg = min(y0 + yl, G0 - 1);
    int zg = min(z0 + zl, G0 - 1);
    size_t base = ((size_t)zg * G0 + yg) * G0 + xg;
    float v0 = ib[base];
    float v1 = ib[base + 512000];
    float v2 = ib[base + 2 * 512000];
    float v3 = ib[base + 3 * 512000];
    uint2 pk = {pk2(v0, v1), pk2(v2, v3)};
    *(uint2*)(raw + p * 4) = pk;
  }
  __syncthreads();

  int wv = tid >> 6, ln = tid & 63, q = ln >> 4, mr = ln & 15;

  bf16x8 Bf[4][2];
#pragma unroll
  for (int s = 0; s < 4; s++)
#pragma unroll
    for (int nt = 0; nt < 2; nt++)
      Bf[s][nt] = *(const bf16x8*)(wB1 + (nt * 16 + mr) * 128 + s * 32 + q * 8);

  f32x4 acc[4][2];
#pragma unroll
  for (int mi = 0; mi < 4; mi++)
#pragma unroll
    for (int nt = 0; nt < 2; nt++) acc[mi][nt] = (f32x4){0.f, 0.f, 0.f, 0.f};

#pragma unroll
  for (int s = 0; s < 4; s++) {
    int tA = min(s * 8 + q * 2, 26);
    int tB = min(s * 8 + q * 2 + 1, 26);
    int oA = (tA / 9) * 108 + ((tA / 3) % 3) * 18 + (tA % 3);
    int oB = (tB / 9) * 108 + ((tB / 3) % 3) * 18 + (tB % 3);
#pragma unroll
    for (int mi = 0; mi < 4; mi++) {
      int pbase = wv * 108 + mi * 18 + mr;
      bf16x8 af;
      *(bf16x4*)&af = *(const bf16x4*)(raw + (pbase + oA) * 4);
      *((bf16x4*)&af + 1) = *(const bf16x4*)(raw + (pbase + oB) * 4);
      acc[mi][0] = __builtin_amdgcn_mfma_f32_16x16x32_bf16(af, Bf[s][0], acc[mi][0], 0, 0, 0);
      acc[mi][1] = __builtin_amdgcn_mfma_f32_16x16x32_bf16(af, Bf[s][1], acc[mi][1], 0, 0, 0);
    }
  }

  __syncthreads();
  float* sout = (float*)smemc;
#pragma unroll
  for (int mi = 0; mi < 4; mi++) {
    int mtile = wv * 4 + mi;
#pragma unroll
    for (int nt = 0; nt < 2; nt++) {
#pragma unroll
      for (int r = 0; r < 4; r++) {
        int pl = mtile * 16 + q * 4 + r;
        sout[pl * 34 + nt * 16 + mr] = acc[mi][nt][r];
      }
    }
  }
  __syncthreads();

  int xl = tid & 15, yl = (tid >> 4) & 3, zl = tid >> 6;
  int xg = x0 + xl, yg = y0 + yl, zg = z0 + zl;
  if (xg < D1 && yg < D1 && zg < D1) {
    float v[C];
#pragma unroll
    for (int c = 0; c < C; c++) v[c] = fmaxf(sout[tid * 34 + c] + bias[c], 0.f);
    unsigned short* op = out + ((size_t)b * D1S + (size_t)zg * (D1 * D1) + (size_t)yg * D1 + xg) * C;
#pragma unroll
    for (int g = 0; g < 4; g++) {
      uint4 o;
      o.x = pk2(v[g * 8 + 0], v[g * 8 + 1]);
      o.y = pk2(v[g * 8 + 2], v[g * 8 + 3]);
      o.z = pk2(v[g * 8 + 4], v[g * 8 + 5]);
      o.w = pk2(v[g * 8 + 6], v[g * 8 + 7]);
      ((uint4*)op)[g] = o;
    }
  }
}

// ---------------- MFMA implicit-GEMM conv (32->32) ----------------
template <int DIN, int DOUT, bool DO_LN>
__global__ __launch_bounds__(256) void k_convm(const unsigned short* __restrict__ actin,
                                               const unsigned short* __restrict__ wB,
                                               const float* __restrict__ bias,
                                               const float* __restrict__ lng,
                                               const float* __restrict__ lnb,
                                               unsigned short* __restrict__ actout) {
  constexpr int DIN2 = DIN * DIN;
  constexpr size_t DINS = (size_t)DIN * DIN2;
  constexpr int DOUT2 = DOUT * DOUT;
  constexpr size_t DOUTS = (size_t)DOUT * DOUT2;
  constexpr int NX = (DOUT + 15) / 16, NY = (DOUT + 3) / 4, NZ = (DOUT + 3) / 4;

  __shared__ alignas(16) unsigned short s_halo[648 * 32];

  int bid = blockIdx.x;
  int b = bid / (NX * NY * NZ);
  int t = bid % (NX * NY * NZ);
  int tx = t % NX;
  int t2 = t / NX;
  int ty = t2 % NY;
  int tz = t2 / NY;
  int x0 = tx * 16, y0 = ty * 4, z0 = tz * 4;
  const unsigned short* ib = actin + (size_t)b * DINS * 32;

  int tid = threadIdx.x;
  for (int ck = tid; ck < 2592; ck += 256) {
    int pos = ck >> 2, sub = ck & 3;
    int xl = pos % 18;
    int p2 = pos / 18;
    int yl = p2 % 6;
    int zl = p2 / 6;
    int xg = min(x0 + xl, DIN - 1);
    int yg = min(y0 + yl, DIN - 1);
    int zg = min(z0 + zl, DIN - 1);
    uint4 v = *(const uint4*)(ib + ((size_t)zg * DIN2 + (size_t)yg * DIN + xg) * 32 + sub * 8);
    *(uint4*)(s_halo + pos * 32 + sub * 8) = v;
  }
  __syncthreads();

  int wv = tid >> 6, ln = tid & 63, q = ln >> 4, mr = ln & 15;

  f32x4 acc[4][2];
#pragma unroll
  for (int mi = 0; mi < 4; mi++)
#pragma unroll
    for (int nt = 0; nt < 2; nt++) acc[mi][nt] = (f32x4){0.f, 0.f, 0.f, 0.f};

  bf16x8 B0 = *(const bf16x8*)(wB + mr * 32 + q * 8);
  bf16x8 B1 = *(const bf16x8*)(wB + (16 + mr) * 32 + q * 8);
#pragma unroll
  for (int tap = 0; tap < 27; tap++) {
    int dz = tap / 9, dy = (tap / 3) % 3, dx = tap % 3;
    bf16x8 nB0, nB1;
    if (tap < 26) {
      nB0 = *(const bf16x8*)(wB + (tap + 1) * 1024 + mr * 32 + q * 8);
      nB1 = *(const bf16x8*)(wB + (tap + 1) * 1024 + (16 + mr) * 32 + q * 8);
    }
#pragma unroll
    for (int mi = 0; mi < 4; mi++) {
      bf16x8 Af = *(const bf16x8*)(s_halo +
          ((wv + dz) * 108 + (mi + dy) * 18 + (mr + dx)) * 32 + q * 8);
      acc[mi][0] = __builtin_amdgcn_mfma_f32_16x16x32_bf16(Af, B0, acc[mi][0], 0, 0, 0);
      acc[mi][1] = __builtin_amdgcn_mfma_f32_16x16x32_bf16(Af, B1, acc[mi][1], 0, 0, 0);
    }
    if (tap < 26) { B0 = nB0; B1 = nB1; }
  }

  __syncthreads();
  float* s_out = (float*)s_halo;
#pragma unroll
  for (int mi = 0; mi < 4; mi++) {
    int mtile = wv * 4 + mi;
#pragma unroll
    for (int nt = 0; nt < 2; nt++) {
#pragma unroll
      for (int r = 0; r < 4; r++) {
        int pl = mtile * 16 + q * 4 + r;
        s_out[pl * 34 + nt * 16 + mr] = acc[mi][nt][r];
      }
    }
  }
  __syncthreads();

  int xl = tid & 15, yl = (tid >> 4) & 3, zl = tid >> 6;
  int xg = x0 + xl, yg = y0 + yl, zg = z0 + zl;
  bool valid = (xg < DOUT) && (yg < DOUT) && (zg < DOUT);
  float v[C];
  float s = 0.f, s2 = 0.f;
#pragma unroll
  for (int c = 0; c < C; c++) {
    float x = fmaxf(s_out[tid * 34 + c] + bias[c], 0.f);
    v[c] = x;
    s += x; s2 += x * x;
  }
  if (DO_LN) {
    float m = s * (1.f / C);
    float inv = rsqrtf(s2 * (1.f / C) - m * m + 1e-5f);
#pragma unroll
    for (int c = 0; c < C; c++) v[c] = (v[c] - m) * inv * lng[c] + lnb[c];
  }
  if (valid) {
    unsigned short* op = actout + ((size_t)b * DOUTS + (size_t)zg * DOUT2 + (size_t)yg * DOUT + xg) * 32;
#pragma unroll
    for (int g = 0; g < 4; g++) {
      uint4 o;
      o.x = pk2(v[g * 8 + 0], v[g * 8 + 1]);
      o.y = pk2(v[g * 8 + 2], v[g * 8 + 3]);
      o.z = pk2(v[g * 8 + 4], v[g * 8 + 5]);
      o.w = pk2(v[g * 8 + 6], v[g * 8 + 7]);
      ((uint4*)op)[g] = o;
    }
  }
}

// ---------------- initial qprep: qkB bf16 [b][16][32] + zero red ----------------
__global__ __launch_bounds__(256) void k_qprep(const float* __restrict__ slots_src,
                                               const float* __restrict__ qlng,
                                               const float* __restrict__ qlnb,
                                               const float* __restrict__ qw,
                                               const float* __restrict__ kw,
                                               unsigned short* __restrict__ qkB,
                                               float* __restrict__ red) {
  __shared__ float ln_s[16][SD];
  __shared__ float q_s[16][SD];
  __shared__ float mv[16][2];
  int tid = threadIdx.x;
  for (int o = tid; o < NRED * REDS; o += 256) red[o] = 0.f;
  if (tid < 16) {
    float s = 0.f, s2 = 0.f;
    for (int c = 0; c < SD; c++) { float v = slots_src[tid * SD + c]; s += v; s2 += v * v; }
    float m = s * (1.f / SD);
    mv[tid][0] = m;
    mv[tid][1] = rsqrtf(s2 * (1.f / SD) - m * m + 1e-5f);
  }
  __syncthreads();
  for (int idx = tid; idx < 16 * SD; idx += 256) {
    int r = idx >> 6, c = idx & 63;
    ln_s[r][c] = (slots_src[idx] - mv[r][0]) * mv[r][1] * qlng[c] + qlnb[c];
  }
  __syncthreads();
  for (int o = tid; o < 16 * SD; o += 256) {
    int r = o >> 6, d = o & 63;
    float s = 0.f;
    for (int c = 0; c < SD; c++) s = fmaf(ln_s[r][c], qw[d * SD + c], s);
    q_s[r][d] = s;
  }
  __syncthreads();
  for (int o = tid; o < 1024; o += 256) {
    int b = o >> 9, i = (o >> 5) & 15, c = o & 31;
    unsigned short v = 0;
    if (i < 8) {
      float s = 0.f;
      for (int d = 0; d < SD; d++) s = fmaf(q_s[(b * 8 + i)][d], kw[d * C + c], s);
      v = f2bf(s);
    }
    qkB[o] = v;
  }
}

// ---------------- attention (MFMA dots; NO ticket — kernel boundary is the sync) ----------------
__global__ __launch_bounds__(256) void k_attn(const unsigned short* __restrict__ feat,
                                              const unsigned short* __restrict__ qkB,
                                              float* __restrict__ red,
                                              float* __restrict__ attn_out,
                                              int last) {
  // f_s: 256 rows x 80B packed bf16 = 20480
  // dots_s: 256 x 12 fp32 (8 used)  = 12288 @ 20480
  // a_s: 8 x 264 bf16               = 4224  @ 32768
  __shared__ alignas(16) char smem[36992];
  char* f_s = smem;
  float* dots_s = (float*)(smem + 20480);
  unsigned short* a_s = (unsigned short*)(smem + 32768);

  int tid = threadIdx.x;
  int b = blockIdx.y;
  int wv = tid >> 6, ln = tid & 63, q = ln >> 4, mr = ln & 15;

  int j0 = blockIdx.x * 256;
  int j = j0 + tid;
  bool valid = j < D3S;

  // phase 0: global feat -> LDS rows (packed bf16)
  uint4 f4[4];
  if (valid) {
    const uint4* fp = (const uint4*)(feat + ((size_t)b * D3S + j) * C);
#pragma unroll
    for (int g = 0; g < 4; g++) f4[g] = fp[g];
  } else {
#pragma unroll
    for (int g = 0; g < 4; g++) f4[g] = (uint4){0u, 0u, 0u, 0u};
  }
#pragma unroll
  for (int g = 0; g < 4; g++) *(uint4*)(f_s + tid * 80 + g * 16) = f4[g];

  bf16x8 Bq = *(const bf16x8*)(qkB + b * 512 + mr * 32 + q * 8);
  __syncthreads();

  // phase 1: dots via MFMA (4 m-tiles/wave cover its 64 j)
  f32x4 dacc[4];
#pragma unroll
  for (int mt = 0; mt < 4; mt++) {
    bf16x8 Af = *(const bf16x8*)(f_s + (wv * 64 + mt * 16 + mr) * 80 + q * 16);
    dacc[mt] = __builtin_amdgcn_mfma_f32_16x16x32_bf16(
        Af, Bq, (f32x4){0.f, 0.f, 0.f, 0.f}, 0, 0, 0);
  }
  if (mr < 8) {
#pragma unroll
    for (int mt = 0; mt < 4; mt++)
#pragma unroll
      for (int r = 0; r < 4; r++)
        dots_s[(wv * 64 + mt * 16 + q * 4 + r) * 12 + mr] = dacc[mt][r];
  }
  __syncthreads();

  // softmax over slots (thread = its j)
  float attn[NSLOT];
  {
    uint4 d0 = *(const uint4*)(dots_s + tid * 12);
    uint4 d1 = *(const uint4*)(dots_s + tid * 12 + 4);
    float dot[NSLOT] = {__uint_as_float(d0.x), __uint_as_float(d0.y),
                        __uint_as_float(d0.z), __uint_as_float(d0.w),
                        __uint_as_float(d1.x), __uint_as_float(d1.y),
                        __uint_as_float(d1.z), __uint_as_float(d1.w)};
    float mx = -1e30f;
#pragma unroll
    for (int i = 0; i < NSLOT; i++) { dot[i] *= 0.125f; mx = fmaxf(mx, dot[i]); }
    float ssum = 0.f;
#pragma unroll
    for (int i = 0; i < NSLOT; i++) { float e = __expf(dot[i] - mx); attn[i] = e; ssum += e; }
    float invs = 1.f / ssum;
#pragma unroll
    for (int i = 0; i < NSLOT; i++)
      attn[i] = valid ? fmaf(attn[i], invs, 1e-8f) : 0.f;
  }
#pragma unroll
  for (int i = 0; i < NSLOT; i++)
    a_s[i * 264 + tid + (tid >> 5)] = f2bf(attn[i]);
  if (last && valid) {
#pragma unroll
    for (int i = 0; i < NSLOT; i++)
      attn_out[(size_t)(b * NSLOT + i) * D3S + j] = attn[i];
  }
  __syncthreads();

  // phase 2: thread = (slot i0, j-half h, ch-pair cp); conflict-free banks
  int i0 = tid >> 5;
  int h = (tid >> 4) & 1;
  int cp = tid & 15;
  float acc0 = 0.f, acc1 = 0.f, rs = 0.f;
#pragma unroll 8
  for (int it = 0; it < 128; it++) {
    int jj = h * 128 + it;
    float a = bfu(a_s[i0 * 264 + jj + (jj >> 5)]);
    unsigned int fv = *(const unsigned int*)(f_s + jj * 80 + cp * 4);
    acc0 = fmaf(a, bflo(fv), acc0);
    acc1 = fmaf(a, bfhi(fv), acc1);
    rs += a;
  }
  acc0 += __shfl_xor(acc0, 16);
  acc1 += __shfl_xor(acc1, 16);
  rs   += __shfl_xor(rs, 16);

  int gsl = blockIdx.x & (NRED - 1);
  int r = b * NSLOT + i0;
  if (h == 0) {
    atomicAdd(&red[gsl * REDS + r * 32 + 2 * cp], acc0);
    atomicAdd(&red[gsl * REDS + r * 32 + 2 * cp + 1], acc1);
    if (cp == 0) atomicAdd(&red[gsl * REDS + 512 + r], rs);
  }
}

// ---------------- final: reduce red + vw proj + GRU + LN + MLP + next qprep ----------------
__global__ __launch_bounds__(256) void k_final(const float* __restrict__ slots_src,
                                               float* __restrict__ red,
                                               const float* __restrict__ vw,
                                               const float* __restrict__ wih,
                                               const float* __restrict__ whh,
                                               const float* __restrict__ bih,
                                               const float* __restrict__ bhh,
                                               const float* __restrict__ rlng,
                                               const float* __restrict__ rlnb,
                                               const float* __restrict__ w1,
                                               const float* __restrict__ rb1,
                                               const float* __restrict__ w2,
                                               const float* __restrict__ rb2,
                                               const float* __restrict__ qlng,
                                               const float* __restrict__ qlnb,
                                               const float* __restrict__ qw,
                                               const float* __restrict__ kw,
                                               unsigned short* __restrict__ qkB,
                                               float* __restrict__ slots_dst,
                                               float* __restrict__ out_slots,
                                               int last) {
  __shared__ float updc[16][33];
  __shared__ float rs_s[16];
  __shared__ float hh[16][64], upd_s[16][64];
  __shared__ float xg[16][192], hg[16][192];
  __shared__ float hn[16][64], tl[16][64], m1[16][128], qbuf[16][64];
  __shared__ float mv[16][2];
  int tid = threadIdx.x;

  if (tid < 16) {
    float sr = 0.f;
#pragma unroll
    for (int g = 0; g < NRED; g++) sr += red[g * REDS + 512 + tid];
    rs_s[tid] = sr;
  }
  for (int o = tid; o < 512; o += 256) {
    float s = 0.f;
#pragma unroll
    for (int g = 0; g < NRED; g++) s += red[g * REDS + o];
    updc[o >> 5][o & 31] = s;
  }
  for (int idx = tid; idx < 1024; idx += 256) hh[idx >> 6][idx & 63] = slots_src[idx];
  __syncthreads();
  for (int o = tid; o < 1024; o += 256) {
    int rr = o >> 6, dd = o & 63;
    float s = 0.f;
    for (int cc = 0; cc < 32; cc++) s = fmaf(updc[rr][cc], vw[dd * 32 + cc], s);
    upd_s[rr][dd] = s / rs_s[rr];
  }
  __syncthreads();
  for (int o = tid; o < 6144; o += 256) {
    int sel = o >= 3072;
    int oo = o - sel * 3072;
    int rr = oo / 192, cg = oo % 192;
    const float* sp = sel ? &hh[rr][0] : &upd_s[rr][0];
    const float* w = sel ? whh : wih;
    float s = sel ? bhh[cg] : bih[cg];
    for (int dd = 0; dd < 64; dd++) s = fmaf(sp[dd], w[cg * 64 + dd], s);
    float* dp = sel ? &hg[rr][0] : &xg[rr][0];
    dp[cg] = s;
  }
  __syncthreads();
  for (int idx = tid; idx < 1024; idx += 256) {
    int rr = idx >> 6, dd = idx & 63;
    float rg = 1.f / (1.f + __expf(-(xg[rr][dd] + hg[rr][dd])));
    float zg_ = 1.f / (1.f + __expf(-(xg[rr][64 + dd] + hg[rr][64 + dd])));
    float ng = tanhf(xg[rr][128 + dd] + rg * hg[rr][128 + dd]);
    hn[rr][dd] = (1.f - zg_) * ng + zg_ * hh[rr][dd];
  }
  __syncthreads();
  if (tid < 16) {
    float s = 0.f, s2 = 0.f;
    for (int cc = 0; cc < 64; cc++) { float v = hn[tid][cc]; s += v; s2 += v * v; }
    float m = s * (1.f / 64);
    mv[tid][0] = m;
    mv[tid][1] = rsqrtf(s2 * (1.f / 64) - m * m + 1e-5f);
  }
  __syncthreads();
  for (int idx = tid; idx < 1024; idx += 256) {
    int rr = idx >> 6, dd = idx & 63;
    tl[rr][dd] = (hn[rr][dd] - mv[rr][0]) * mv[rr][1] * rlng[dd] + rlnb[dd];
  }
  __syncthreads();
  for (int o = tid; o < 2048; o += 256) {
    int rr = o >> 7, jj = o & 127;
    float s = rb1[jj];
    for (int dd = 0; dd < 64; dd++) s = fmaf(tl[rr][dd], w1[jj * 64 + dd], s);
    m1[rr][jj] = fmaxf(s, 0.f);
  }
  __syncthreads();
  for (int idx = tid; idx < 1024; idx += 256) {
    int rr = idx >> 6, dd = idx & 63;
    float s = rb2[dd];
    for (int jj = 0; jj < 128; jj++) s = fmaf(m1[rr][jj], w2[dd * 128 + jj], s);
    float outv = hn[rr][dd] + s;
    slots_dst[idx] = outv;
    hh[rr][dd] = outv;
    if (last) out_slots[idx] = outv;
  }
  __syncthreads();
  // next-iter qprep
  if (tid < 16) {
    float s = 0.f, s2 = 0.f;
    for (int cc = 0; cc < 64; cc++) { float v = hh[tid][cc]; s += v; s2 += v * v; }
    float m = s * (1.f / 64);
    mv[tid][0] = m;
    mv[tid][1] = rsqrtf(s2 * (1.f / 64) - m * m + 1e-5f);
  }
  __syncthreads();
  for (int idx = tid; idx < 1024; idx += 256) {
    int rr = idx >> 6, dd = idx & 63;
    tl[rr][dd] = (hh[rr][dd] - mv[rr][0]) * mv[rr][1] * qlng[dd] + qlnb[dd];
  }
  __syncthreads();
  for (int o = tid; o < 1024; o += 256) {
    int rr = o >> 6, d = o & 63;
    float s = 0.f;
    for (int cc = 0; cc < 64; cc++) s = fmaf(tl[rr][cc], qw[d * 64 + cc], s);
    qbuf[rr][d] = s;
  }
  __syncthreads();
  for (int o = tid; o < 1024; o += 256) {
    int bb = o >> 9, ii = (o >> 5) & 15, cc = o & 31;
    unsigned short v = 0;
    if (ii < 8) {
      float s = 0.f;
      for (int d = 0; d < 64; d++) s = fmaf(qbuf[bb * 8 + ii][d], kw[d * 32 + cc], s);
      v = f2bf(s);
    }
    qkB[o] = v;
  }
  for (int o = tid; o < NRED * REDS; o += 256) red[o] = 0.f;
}

// ---------------- host launch ----------------
extern "C" void kernel_launch(void* const* d_in, const int* in_sizes, int n_in,
                              void* d_out, int out_size, void* d_ws, size_t ws_size,
                              hipStream_t stream) {
  const float* slots = (const float*)d_in[0];
  const float* oin   = (const float*)d_in[1];
  const float* w1    = (const float*)d_in[2];
  const float* b1    = (const float*)d_in[3];
  const float* w2    = (const float*)d_in[4];
  const float* b2    = (const float*)d_in[5];
  const float* w3    = (const float*)d_in[6];
  const float* b3    = (const float*)d_in[7];
  const float* kw    = (const float*)d_in[8];
  const float* vw    = (const float*)d_in[9];
  const float* qlng  = (const float*)d_in[10];
  const float* qlnb  = (const float*)d_in[11];
  const float* qw    = (const float*)d_in[12];
  const float* wih   = (const float*)d_in[13];
  const float* whh   = (const float*)d_in[14];
  const float* bih   = (const float*)d_in[15];
  const float* bhh   = (const float*)d_in[16];
  const float* rlng  = (const float*)d_in[17];
  const float* rlnb  = (const float*)d_in[18];
  const float* rw1   = (const float*)d_in[19];
  const float* rb1   = (const float*)d_in[20];
  const float* rw2   = (const float*)d_in[21];
  const float* rb2   = (const float*)d_in[22];
  const float* flng  = (const float*)d_in[23];
  const float* flnb  = (const float*)d_in[24];

  char* ws = (char*)d_ws;
  unsigned short* act1 = (unsigned short*)ws;
  unsigned short* act2 = (unsigned short*)(ws + A1_BYTES);
  unsigned short* feat = act1;
  unsigned short* wB1 = (unsigned short*)(ws + S_OFF);
  unsigned short* wB2 = wB1 + 4096;
  unsigned short* wB3 = wB2 + 27648;
  unsigned short* qkB = wB3 + 27648;           // [2][16][32] bf16
  float* red  = (float*)(qkB + 1024);          // NRED*REDS floats
  float* sl0  = red + NRED * REDS;
  float* sl1  = sl0 + 1024;

  float* out_slots = (float*)d_out;
  float* attn_out  = (float*)d_out + 1024;

  k_wtr<<<232, 256, 0, stream>>>(w1, w2, w3, wB1, wB2, wB3);
  k_conv1m<<<C1NX * C1NY * C1NZ * BATCH, 256, 0, stream>>>(oin, wB1, b1, act1);
  {
    constexpr int NB2 = ((D2 + 15) / 16) * ((D2 + 3) / 4) * ((D2 + 3) / 4) * BATCH;
    k_convm<D1, D2, false><<<NB2, 256, 0, stream>>>(act1, wB2, b2, nullptr, nullptr, act2);
  }
  {
    constexpr int NB3 = ((D3 + 15) / 16) * ((D3 + 3) / 4) * ((D3 + 3) / 4) * BATCH;
    k_convm<D2, D3, true><<<NB3, 256, 0, stream>>>(act2, wB3, b3, flng, flnb, feat);
  }

  k_qprep<<<1, 256, 0, stream>>>(slots, qlng, qlnb, qw, kw, qkB, red);
  const float* src = slots;
  float* dst = sl0;
  for (int it = 0; it < 3; it++) {
    int last = (it == 2);
    k_attn<<<dim3(NCHUNK, BATCH), 256, 0, stream>>>(feat, qkB, red, attn_out, last);
    k_final<<<1, 256, 0, stream>>>(src, red, vw, wih, whh, bih, bhh,
                                   rlng, rlnb, rw1, rb1, rw2, rb2,
                                   qlng, qlnb, qw, kw, qkB, dst, out_slots, last);
    src = dst;
    dst = (it == 0) ? sl1 : sl0;
  }
}